// Round 11
// baseline (414.251 us; speedup 1.0000x reference)
//
#include <hip/hip_runtime.h>
#include <math.h>

#define NBATCH 2
#define CHN    64
#define NYY    80
#define NXX    80
#define NCLS   80
#define NPIX   6400      // 80*80
#define KTOT   512000    // NCLS*NPIX
#define NOUT   85        // 5 + NCLS

typedef float vf4 __attribute__((ext_vector_type(4)));

// output = 87,040,000 floats = 21,760,000 float4 quads
#define QTOT   21760000L
#define QF1    13056000L     // conv1: 60%
#define QF2    17856000L     // conv2 fused: 22%
                             // scatter: 18% (QF2..QTOT)

// ============ K1: fused 3x3 conv + ReLU (hm fp64-acc | wh/reg fp32) ============
// EXACT round-9 structure (154 µs pipeline). grid 640 x 320 thr, 39,936 B LDS.
__global__ __launch_bounds__(320)
void conv1_kernel(const float* __restrict__ x,
                  const float* __restrict__ hw1, const float* __restrict__ hb1,
                  const float* __restrict__ ww1, const float* __restrict__ wb1,
                  const float* __restrict__ rw1, const float* __restrict__ rb1,
                  double* __restrict__ c1hm, float* __restrict__ c1wr,
                  vf4* __restrict__ outq)
{
    __shared__ double smem_d[4992];    // 39,936 B shared by both paths
    const int bl = blockIdx.x;
    const int t  = threadIdx.x;

    const int gtid = bl * 320 + t;
    const int nth  = 640 * 320;        // 204800
    const vf4 fz = {0.f, 0.f, 0.f, 0.f};

    if (bl < 320) {
        // ---------------- hm path: fp64 acc, float x-LDS ----------------
        float*  lxf = (float*)smem_d;                    // [16][4][84] = 21,504 B
        double* lwd = (double*)((char*)smem_d + 21504);  // [144][16]   = 18,432 B

        const int yt  = bl % 40;
        const int ocg = (bl / 40) % 4;
        const int b   = bl / 160;

        const int pxq = t % 80;        // 2-px group
        const int ocq = t / 80;        // 0..3
        const int r   = pxq / 40;      // tile row 0..1
        const int c   = (pxq % 40) * 2;
        const int oc0 = ocg * 16 + ocq * 4;
        const int gy0 = yt * 2;

        const float* xin = x + (size_t)b * CHN * NPIX;

        double acc[2][4];
        #pragma unroll
        for (int j = 0; j < 2; j++)
            #pragma unroll
            for (int o = 0; o < 4; o++) acc[j][o] = (double)hb1[oc0 + o];

        for (int cc = 0; cc < 4; cc++) {
            const int icc = cc * 16;
            __syncthreads();
            for (int j = t; j < 1280; j += 320) {
                int ic_l = j / 80; int rem = j % 80;
                int row_l = rem / 20; int c4 = (rem % 20) * 4;
                int gy = gy0 - 1 + row_l;
                float4 v = make_float4(0.f, 0.f, 0.f, 0.f);
                if ((unsigned)gy < 80u)
                    v = *(const float4*)(xin + (size_t)(icc + ic_l) * NPIX + gy * NXX + c4);
                float* dst = &lxf[(ic_l * 4 + row_l) * 84];
                dst[c4 + 1] = v.x; dst[c4 + 2] = v.y;
                dst[c4 + 3] = v.z; dst[c4 + 4] = v.w;
            }
            for (int j = t; j < 64; j += 320) {
                lxf[j * 84 + 0]  = 0.f;
                lxf[j * 84 + 81] = 0.f;
            }
            for (int j = t; j < 2304; j += 320) {
                int oc_l = j % 16; int k = j / 16;
                int ic_l = k / 9, tap = k % 9;
                lwd[k * 16 + oc_l] =
                    (double)hw1[((size_t)(ocg * 16 + oc_l) * CHN + icc + ic_l) * 9 + tap];
            }
            __syncthreads();
            {   // zero-fill slice (drains under fp64 compute)
                int i0 = cc * 16, i1 = i0 + 16;
                for (int i = i0; i < i1; i++) {
                    long q = (long)gtid + (long)i * nth;
                    if (q < QF1) __builtin_nontemporal_store(fz, outq + q);
                }
            }
            for (int ic = 0; ic < 16; ic++) {
                double xw[3][4];
                #pragma unroll
                for (int ky = 0; ky < 3; ky++) {
                    const float* row = &lxf[(ic * 4 + r + ky) * 84];
                    float2 a  = *(const float2*)&row[c];
                    float2 bb = *(const float2*)&row[c + 2];
                    xw[ky][0] = (double)a.x;  xw[ky][1] = (double)a.y;
                    xw[ky][2] = (double)bb.x; xw[ky][3] = (double)bb.y;
                }
                #pragma unroll
                for (int ky = 0; ky < 3; ky++)
                #pragma unroll
                for (int kx = 0; kx < 3; kx++) {
                    const double* wv = &lwd[(ic * 9 + ky * 3 + kx) * 16 + ocq * 4];
                    double w0 = wv[0], w1d = wv[1], w2 = wv[2], w3 = wv[3];
                    double x0 = xw[ky][kx], x1 = xw[ky][kx + 1];
                    acc[0][0] += x0 * w0; acc[0][1] += x0 * w1d;
                    acc[0][2] += x0 * w2; acc[0][3] += x0 * w3;
                    acc[1][0] += x1 * w0; acc[1][1] += x1 * w1d;
                    acc[1][2] += x1 * w2; acc[1][3] += x1 * w3;
                }
            }
        }
        size_t pix = (size_t)(gy0 + r) * NXX + c;
        #pragma unroll
        for (int o = 0; o < 4; o++) {
            double2 v;
            v.x = acc[0][o] > 0.0 ? acc[0][o] : 0.0;
            v.y = acc[1][o] > 0.0 ? acc[1][o] : 0.0;
            *(double2*)(c1hm + ((size_t)b * CHN + oc0 + o) * NPIX + pix) = v;
        }
    } else {
        // ---------------- wh/reg path: fp32, 4-row tiles ----------------
        float* lxw = (float*)smem_d;                     // [16][6][80] = 30,720 B
        float* lwf = (float*)((char*)smem_d + 30720);    // [144][16]   =  9,216 B

        const int blw = bl - 320;
        const int yt  = blw % 20;
        const int ocg = (blw / 20) % 4;
        const int img = blw / 80;      // 0=wh b0, 1=wh b1, 2=reg b0, 3=reg b1

        const int head = img >> 1, b = img & 1;
        const float* w1 = (head == 0) ? ww1 : rw1;
        const float* b1 = (head == 0) ? wb1 : rb1;
        const float* xin = x + (size_t)b * CHN * NPIX;

        const int pxq = t % 80;
        const int ocq = t / 80;
        const int r   = pxq / 20;
        const int c   = (pxq % 20) * 4;
        const int oc0 = ocg * 16 + ocq * 4;
        const int gy0 = yt * 4;

        float acc[4][4];
        #pragma unroll
        for (int j = 0; j < 4; j++)
            #pragma unroll
            for (int o = 0; o < 4; o++) acc[j][o] = b1[oc0 + o];

        for (int cc = 0; cc < 4; cc++) {
            const int icc = cc * 16;
            __syncthreads();
            for (int j = t; j < 1920; j += 320) {
                int ic_l = j / 120; int rem = j % 120;
                int row_l = rem / 20; int c4 = (rem % 20) * 4;
                int gy = gy0 - 1 + row_l;
                float4 v = make_float4(0.f, 0.f, 0.f, 0.f);
                if ((unsigned)gy < 80u)
                    v = *(const float4*)(xin + (size_t)(icc + ic_l) * NPIX + gy * NXX + c4);
                *(float4*)&lxw[(ic_l * 6 + row_l) * 80 + c4] = v;
            }
            for (int j = t; j < 2304; j += 320) {
                int oc_l = j % 16; int k = j / 16;
                int ic_l = k / 9, tap = k % 9;
                lwf[k * 16 + oc_l] =
                    w1[((size_t)(ocg * 16 + oc_l) * CHN + icc + ic_l) * 9 + tap];
            }
            __syncthreads();
            {
                int i0 = cc * 16, i1 = i0 + 16;
                for (int i = i0; i < i1; i++) {
                    long q = (long)gtid + (long)i * nth;
                    if (q < QF1) __builtin_nontemporal_store(fz, outq + q);
                }
            }
            for (int ic = 0; ic < 16; ic++) {
                float xw[3][6];
                #pragma unroll
                for (int ky = 0; ky < 3; ky++) {
                    const float* row = &lxw[(ic * 6 + r + ky) * 80];
                    xw[ky][0] = (c > 0) ? row[c - 1] : 0.f;
                    float4 m = *(const float4*)&row[c];
                    xw[ky][1] = m.x; xw[ky][2] = m.y;
                    xw[ky][3] = m.z; xw[ky][4] = m.w;
                    xw[ky][5] = (c < 76) ? row[c + 4] : 0.f;
                }
                #pragma unroll
                for (int ky = 0; ky < 3; ky++)
                #pragma unroll
                for (int kx = 0; kx < 3; kx++) {
                    const float* wv = &lwf[(ic * 9 + ky * 3 + kx) * 16 + ocq * 4];
                    float w0 = wv[0], w1v = wv[1], w2 = wv[2], w3 = wv[3];
                    #pragma unroll
                    for (int j = 0; j < 4; j++) {
                        float xv = xw[ky][j + kx];
                        acc[j][0] += xv * w0; acc[j][1] += xv * w1v;
                        acc[j][2] += xv * w2; acc[j][3] += xv * w3;
                    }
                }
            }
        }
        size_t pix = (size_t)(gy0 + r) * NXX + c;
        #pragma unroll
        for (int o = 0; o < 4; o++) {
            float4 v;
            v.x = fmaxf(acc[0][o], 0.f); v.y = fmaxf(acc[1][o], 0.f);
            v.z = fmaxf(acc[2][o], 0.f); v.w = fmaxf(acc[3][o], 0.f);
            *(float4*)(c1wr + ((size_t)img * CHN + oc0 + o) * NPIX + pix) = v;
        }
    }
}

// ============ K2: FUSED conv2_hm (fp64 logits) + 3x3 maxima + conv2_wr ============
// grid 960 x 320 thr.
// bl < 800: hm+flags. bl = (b*20 + cg)*20 + rt. 4 classes (cg*4..+3), 4 rows (rt*4..+3).
//           Computes strip + halo rows into LDS (halo recomputed), flags, ballots, counts.
// bl >= 800: wr. blw: chunk=blw%20 (320 px), hc=(blw/20)%4, b=blw/80.
__global__ __launch_bounds__(320)
void conv2_kernel(const double* __restrict__ c1hm,
                  const float* __restrict__ hm_w2, const float* __restrict__ hm_b2,
                  const float* __restrict__ c1wr,
                  const float* __restrict__ wh_w2, const float* __restrict__ wh_b2,
                  const float* __restrict__ rg_w2, const float* __restrict__ rg_b2,
                  double* __restrict__ hm_z, float* __restrict__ wh, float* __restrict__ rg,
                  unsigned long long* __restrict__ ballots,
                  unsigned int* __restrict__ counts,
                  vf4* __restrict__ outq)
{
    __shared__ double lz[4][6][80];     // 15,360 B  (rows y0-1 .. y0+4)
    __shared__ double lw[64][4];        //  2,048 B
    __shared__ unsigned int wcnt[4][5];

    const int bl = blockIdx.x;
    const int t  = threadIdx.x;

    // zero-fill slice (drains under compute)
    {
        const int gtid = bl * 320 + t;
        const vf4 fz = {0.f, 0.f, 0.f, 0.f};
        for (int i = 0; i < 16; i++) {
            long q = QF1 + (long)gtid + (long)i * 307200;
            if (q < QF2) __builtin_nontemporal_store(fz, outq + q);
        }
    }

    if (bl < 800) {
        const int rt = bl % 20;
        const int cg = (bl / 20) % 20;
        const int b  = bl / 400;
        const int y0 = rt * 4;

        if (t < 256) {
            int ic = t & 63, o = t >> 6;
            lw[ic][o] = (double)hm_w2[(size_t)(cg * 4 + o) * CHN + ic];
        }
        __syncthreads();

        const double* in = c1hm + (size_t)b * CHN * NPIX;
        double bias[4];
        #pragma unroll
        for (int o = 0; o < 4; o++) bias[o] = (double)hm_b2[cg * 4 + o];

        for (int j = t; j < 480; j += 320) {
            int jr = j / 80, px = j % 80;
            int gy = y0 - 1 + jr;
            double z0 = -1.0e300, z1 = -1.0e300, z2 = -1.0e300, z3 = -1.0e300;
            if ((unsigned)gy < 80u) {
                int p = gy * 80 + px;
                double a0 = bias[0], a1 = bias[1], a2 = bias[2], a3 = bias[3];
                for (int ic = 0; ic < CHN; ic++) {
                    double xv = in[(size_t)ic * NPIX + p];
                    a0 += xv * lw[ic][0]; a1 += xv * lw[ic][1];
                    a2 += xv * lw[ic][2]; a3 += xv * lw[ic][3];
                }
                z0 = a0; z1 = a1; z2 = a2; z3 = a3;
                if (jr >= 1 && jr <= 4) {   // interior rows only (owned by this block)
                    hm_z[((size_t)b * NCLS + cg * 4 + 0) * NPIX + p] = z0;
                    hm_z[((size_t)b * NCLS + cg * 4 + 1) * NPIX + p] = z1;
                    hm_z[((size_t)b * NCLS + cg * 4 + 2) * NPIX + p] = z2;
                    hm_z[((size_t)b * NCLS + cg * 4 + 3) * NPIX + p] = z3;
                }
            }
            lz[0][jr][px] = z0; lz[1][jr][px] = z1;
            lz[2][jr][px] = z2; lz[3][jr][px] = z3;
        }
        __syncthreads();

        const int wave = t >> 6, lane = t & 63;
        const int idx = wave * 64 + lane;       // 0..319
        const int ry = idx / 80, px = idx % 80;
        #pragma unroll
        for (int o = 0; o < 4; o++) {
            double s = lz[o][ry + 1][px];
            double m = s;
            #pragma unroll
            for (int dy = -1; dy <= 1; dy++) {
                const double* row = &lz[o][ry + 1 + dy][0];
                #pragma unroll
                for (int dx = -1; dx <= 1; dx++) {
                    int xn = px + dx;
                    if ((unsigned)xn < 80u) {
                        double v = row[xn];
                        m = v > m ? v : m;
                    }
                }
            }
            bool flag = (s == m);
            unsigned long long ball = __ballot(flag);
            if (lane == 0) {
                int c = cg * 4 + o;
                ballots[(size_t)b * 8000 + c * 100 + rt * 5 + wave] = ball;
                wcnt[o][wave] = __popcll(ball);
            }
        }
        __syncthreads();
        if (t < 4) {
            unsigned int tot = 0;
            #pragma unroll
            for (int w = 0; w < 5; w++) tot += wcnt[t][w];
            counts[b * 1600 + (cg * 4 + t) * 20 + rt] = tot;
        }
    } else {
        const int blw  = bl - 800;
        const int chunk = blw % 20;
        const int hc   = (blw / 20) % 4;
        const int b    = blw / 80;
        const int head = hc >> 1, ch = hc & 1;

        const int p = chunk * 320 + t;
        const float* in = c1wr + ((size_t)(head * 2 + b) * CHN) * NPIX;
        const float* w  = (head == 0) ? wh_w2 + (size_t)ch * CHN : rg_w2 + (size_t)ch * CHN;
        float acc = (head == 0) ? wh_b2[ch] : rg_b2[ch];
        for (int ic = 0; ic < CHN; ic++) acc += in[(size_t)ic * NPIX + p] * w[ic];
        acc = fmaxf(acc, 0.f);
        float* o = (head == 0) ? wh : rg;
        o[((size_t)b * 2 + ch) * NPIX + p] = acc;
    }
}

// ============ K3: exclusive scan of 1600 segment counts per batch ============
// grid 2 x 1024 thr; 2 entries/thread
__global__ __launch_bounds__(1024)
void scan_kernel(const unsigned int* __restrict__ counts,
                 unsigned int* __restrict__ offs)
{
    int b = blockIdx.x;
    int t = threadIdx.x;
    int i0 = 2 * t, i1 = 2 * t + 1;
    unsigned int e0 = (i0 < 1600) ? counts[b * 1600 + i0] : 0u;
    unsigned int e1 = (i1 < 1600) ? counts[b * 1600 + i1] : 0u;
    unsigned int s = e0 + e1;
    unsigned int xi = s;
    #pragma unroll
    for (int d = 1; d < 64; d <<= 1) {
        unsigned int n = __shfl_up(xi, d, 64);
        if ((t & 63) >= d) xi += n;
    }
    __shared__ unsigned int wtot[16];
    __shared__ unsigned int wbase[16];
    if ((t & 63) == 63) wtot[t >> 6] = xi;
    __syncthreads();
    if (t == 0) {
        unsigned int a = 0;
        for (int i = 0; i < 16; i++) { wbase[i] = a; a += wtot[i]; }
    }
    __syncthreads();
    unsigned int excl = xi - s + wbase[t >> 6];
    if (i0 < 1600) offs[b * 1600 + i0] = excl;
    if (i1 < 1600) offs[b * 1600 + i1] = excl + e0;
}

// ============ K4: scatter maxima rows (sigmoid only here) ============
// grid (1600, 2) x 320 thr; one block per (class, row-tile) segment
__global__ __launch_bounds__(320)
void scatter_kernel(const unsigned long long* __restrict__ ballots,
                    const unsigned int* __restrict__ offs,
                    const double* __restrict__ hm_z,
                    const float* __restrict__ wh,
                    const float* __restrict__ rg,
                    const float* __restrict__ offsets,
                    float* __restrict__ out,
                    vf4* __restrict__ outq)
{
    __shared__ unsigned long long lball[5];
    __shared__ unsigned int pre[5];

    const int seg = blockIdx.x;        // c*20 + rt
    const int b   = blockIdx.y;
    const int t   = threadIdx.x;
    const int c   = seg / 20, rt = seg % 20;

    // zero-fill tail slice (batch-1 rows >= ~328K; actual maxima ~60K)
    {
        const int gtid = (b * 1600 + seg) * 320 + t;
        const vf4 fz = {0.f, 0.f, 0.f, 0.f};
        for (int i = 0; i < 4; i++) {
            long q = QF2 + (long)gtid + (long)i * 1024000;
            if (q < QTOT) __builtin_nontemporal_store(fz, outq + q);
        }
    }

    if (t < 5) {
        unsigned long long ball = ballots[(size_t)b * 8000 + c * 100 + rt * 5 + t];
        lball[t] = ball;
        pre[t] = __popcll(ball);
    }
    __syncthreads();
    if (t == 0) {
        unsigned int run = offs[b * 1600 + seg];
        #pragma unroll
        for (int i = 0; i < 5; i++) { unsigned int v = pre[i]; pre[i] = run; run += v; }
    }
    __syncthreads();

    const int wave = t >> 6, lane = t & 63;
    unsigned long long ball = lball[wave];
    if (!((ball >> lane) & 1ull)) return;

    unsigned int rank = pre[wave]
                      + (unsigned int)__popcll(ball & ((1ull << lane) - 1ull));

    const int idx = wave * 64 + lane;  // 0..319 within segment
    const int y = rt * 4 + idx / 80;
    const int xx = idx % 80;
    const int p = y * 80 + xx;

    float offx = offsets[b * 3 + 1];
    float offy = offsets[b * 3 + 2];
    float r0 = rg[((size_t)b * 2 + 0) * NPIX + p];
    float r1 = rg[((size_t)b * 2 + 1) * NPIX + p];
    float w0 = wh[((size_t)b * 2 + 0) * NPIX + p];
    float w1 = wh[((size_t)b * 2 + 1) * NPIX + p];
    double z = hm_z[((size_t)b * NCLS + c) * NPIX + p];
    float s  = (float)(1.0 / (1.0 + exp(-z)));

    float cx = ((float)xx + 2.f * offx + r0) * 4.f;
    float cy = ((float)y  + 2.f * offy + r1) * 4.f;

    float* row = out + ((size_t)b * KTOT + rank) * NOUT;
    row[0] = cx;
    row[1] = cy;
    row[2] = w0 * 4.f;
    row[3] = w1 * 4.f;
    row[4] = s;
    row[5 + c] = 1.f;
}

extern "C" void kernel_launch(void* const* d_in, const int* in_sizes, int n_in,
                              void* d_out, int out_size, void* d_ws, size_t ws_size,
                              hipStream_t stream)
{
    const float* x       = (const float*)d_in[0];
    const float* offsets = (const float*)d_in[1];
    const float* hm_w1   = (const float*)d_in[2];
    const float* hm_b1   = (const float*)d_in[3];
    const float* hm_w2   = (const float*)d_in[4];
    const float* hm_b2   = (const float*)d_in[5];
    const float* wh_w1   = (const float*)d_in[6];
    const float* wh_b1   = (const float*)d_in[7];
    const float* wh_w2   = (const float*)d_in[8];
    const float* wh_b2   = (const float*)d_in[9];
    const float* reg_w1  = (const float*)d_in[10];
    const float* reg_b1  = (const float*)d_in[11];
    const float* reg_w2  = (const float*)d_in[12];
    const float* reg_b2  = (const float*)d_in[13];

    float* out = (float*)d_out;
    vf4* outq  = (vf4*)d_out;

    // workspace layout
    char* wp = (char*)d_ws;
    double* c1hm = (double*)wp;                 wp += (size_t)NBATCH * CHN * NPIX * 8;
    double* hm_z = (double*)wp;                 wp += (size_t)NBATCH * NCLS * NPIX * 8;
    float*  c1wr = (float*)wp;                  wp += (size_t)2 * NBATCH * CHN * NPIX * 4;
    float*  wh   = (float*)wp;                  wp += (size_t)NBATCH * 2 * NPIX * 4;
    float*  rg   = (float*)wp;                  wp += (size_t)NBATCH * 2 * NPIX * 4;
    unsigned long long* ballots = (unsigned long long*)wp; wp += (size_t)NBATCH * 8000 * 8;
    unsigned int* counts = (unsigned int*)wp;   wp += (size_t)NBATCH * 1600 * 4;
    unsigned int* offs   = (unsigned int*)wp;

    conv1_kernel<<<640, 320, 0, stream>>>(
        x, hm_w1, hm_b1, wh_w1, wh_b1, reg_w1, reg_b1, c1hm, c1wr, outq);

    conv2_kernel<<<960, 320, 0, stream>>>(
        c1hm, hm_w2, hm_b2, c1wr, wh_w2, wh_b2, reg_w2, reg_b2,
        hm_z, wh, rg, ballots, counts, outq);

    scan_kernel<<<2, 1024, 0, stream>>>(counts, offs);

    scatter_kernel<<<dim3(1600, 2), 320, 0, stream>>>(
        ballots, offs, hm_z, wh, rg, offsets, out, outq);
}

// Round 12
// 158.630 us; speedup vs baseline: 2.6114x; 2.6114x over previous
//
#include <hip/hip_runtime.h>
#include <math.h>

#define NBATCH 2
#define CHN    64
#define NYY    80
#define NXX    80
#define NCLS   80
#define NPIX   6400      // 80*80
#define KTOT   512000    // NCLS*NPIX
#define NOUT   85        // 5 + NCLS
#define NBLK   500       // KTOT / 1024

typedef float vf4 __attribute__((ext_vector_type(4)));

// output = 87,040,000 floats = 21,760,000 float4 quads
#define QTOT   21760000L
#define QF1    13056000L     // conv1: 60%
#define QF2    13721600L     // conv2_hm: 3% (13 iters x 51200)
#define QF3    19584000L     // flags: 27%
                             // scatter: 10% (QF3..QTOT)

// ============ K1: fused 3x3 conv + ReLU (hm fp64-acc | wh/reg fp32) ============
// EXACT round-9 structure. grid 640 x 320 thr, 39,936 B LDS.
__global__ __launch_bounds__(320)
void conv1_kernel(const float* __restrict__ x,
                  const float* __restrict__ hw1, const float* __restrict__ hb1,
                  const float* __restrict__ ww1, const float* __restrict__ wb1,
                  const float* __restrict__ rw1, const float* __restrict__ rb1,
                  double* __restrict__ c1hm, float* __restrict__ c1wr,
                  vf4* __restrict__ outq)
{
    __shared__ double smem_d[4992];    // 39,936 B shared by both paths
    const int bl = blockIdx.x;
    const int t  = threadIdx.x;

    const int gtid = bl * 320 + t;
    const int nth  = 640 * 320;        // 204800
    const vf4 fz = {0.f, 0.f, 0.f, 0.f};

    if (bl < 320) {
        // ---------------- hm path: fp64 acc, float x-LDS ----------------
        float*  lxf = (float*)smem_d;                    // [16][4][84] = 21,504 B
        double* lwd = (double*)((char*)smem_d + 21504);  // [144][16]   = 18,432 B

        const int yt  = bl % 40;
        const int ocg = (bl / 40) % 4;
        const int b   = bl / 160;

        const int pxq = t % 80;        // 2-px group
        const int ocq = t / 80;        // 0..3
        const int r   = pxq / 40;      // tile row 0..1
        const int c   = (pxq % 40) * 2;
        const int oc0 = ocg * 16 + ocq * 4;
        const int gy0 = yt * 2;

        const float* xin = x + (size_t)b * CHN * NPIX;

        double acc[2][4];
        #pragma unroll
        for (int j = 0; j < 2; j++)
            #pragma unroll
            for (int o = 0; o < 4; o++) acc[j][o] = (double)hb1[oc0 + o];

        for (int cc = 0; cc < 4; cc++) {
            const int icc = cc * 16;
            __syncthreads();
            for (int j = t; j < 1280; j += 320) {
                int ic_l = j / 80; int rem = j % 80;
                int row_l = rem / 20; int c4 = (rem % 20) * 4;
                int gy = gy0 - 1 + row_l;
                float4 v = make_float4(0.f, 0.f, 0.f, 0.f);
                if ((unsigned)gy < 80u)
                    v = *(const float4*)(xin + (size_t)(icc + ic_l) * NPIX + gy * NXX + c4);
                float* dst = &lxf[(ic_l * 4 + row_l) * 84];
                dst[c4 + 1] = v.x; dst[c4 + 2] = v.y;
                dst[c4 + 3] = v.z; dst[c4 + 4] = v.w;
            }
            for (int j = t; j < 64; j += 320) {
                lxf[j * 84 + 0]  = 0.f;
                lxf[j * 84 + 81] = 0.f;
            }
            for (int j = t; j < 2304; j += 320) {
                int oc_l = j % 16; int k = j / 16;
                int ic_l = k / 9, tap = k % 9;
                lwd[k * 16 + oc_l] =
                    (double)hw1[((size_t)(ocg * 16 + oc_l) * CHN + icc + ic_l) * 9 + tap];
            }
            __syncthreads();
            {   // zero-fill slice (drains under fp64 compute)
                int i0 = cc * 16, i1 = i0 + 16;
                for (int i = i0; i < i1; i++) {
                    long q = (long)gtid + (long)i * nth;
                    if (q < QF1) __builtin_nontemporal_store(fz, outq + q);
                }
            }
            for (int ic = 0; ic < 16; ic++) {
                double xw[3][4];
                #pragma unroll
                for (int ky = 0; ky < 3; ky++) {
                    const float* row = &lxf[(ic * 4 + r + ky) * 84];
                    float2 a  = *(const float2*)&row[c];
                    float2 bb = *(const float2*)&row[c + 2];
                    xw[ky][0] = (double)a.x;  xw[ky][1] = (double)a.y;
                    xw[ky][2] = (double)bb.x; xw[ky][3] = (double)bb.y;
                }
                #pragma unroll
                for (int ky = 0; ky < 3; ky++)
                #pragma unroll
                for (int kx = 0; kx < 3; kx++) {
                    const double* wv = &lwd[(ic * 9 + ky * 3 + kx) * 16 + ocq * 4];
                    double w0 = wv[0], w1d = wv[1], w2 = wv[2], w3 = wv[3];
                    double x0 = xw[ky][kx], x1 = xw[ky][kx + 1];
                    acc[0][0] += x0 * w0; acc[0][1] += x0 * w1d;
                    acc[0][2] += x0 * w2; acc[0][3] += x0 * w3;
                    acc[1][0] += x1 * w0; acc[1][1] += x1 * w1d;
                    acc[1][2] += x1 * w2; acc[1][3] += x1 * w3;
                }
            }
        }
        size_t pix = (size_t)(gy0 + r) * NXX + c;
        #pragma unroll
        for (int o = 0; o < 4; o++) {
            double2 v;
            v.x = acc[0][o] > 0.0 ? acc[0][o] : 0.0;
            v.y = acc[1][o] > 0.0 ? acc[1][o] : 0.0;
            *(double2*)(c1hm + ((size_t)b * CHN + oc0 + o) * NPIX + pix) = v;
        }
    } else {
        // ---------------- wh/reg path: fp32, 4-row tiles ----------------
        float* lxw = (float*)smem_d;                     // [16][6][80] = 30,720 B
        float* lwf = (float*)((char*)smem_d + 30720);    // [144][16]   =  9,216 B

        const int blw = bl - 320;
        const int yt  = blw % 20;
        const int ocg = (blw / 20) % 4;
        const int img = blw / 80;      // 0=wh b0, 1=wh b1, 2=reg b0, 3=reg b1

        const int head = img >> 1, b = img & 1;
        const float* w1 = (head == 0) ? ww1 : rw1;
        const float* b1 = (head == 0) ? wb1 : rb1;
        const float* xin = x + (size_t)b * CHN * NPIX;

        const int pxq = t % 80;
        const int ocq = t / 80;
        const int r   = pxq / 20;
        const int c   = (pxq % 20) * 4;
        const int oc0 = ocg * 16 + ocq * 4;
        const int gy0 = yt * 4;

        float acc[4][4];
        #pragma unroll
        for (int j = 0; j < 4; j++)
            #pragma unroll
            for (int o = 0; o < 4; o++) acc[j][o] = b1[oc0 + o];

        for (int cc = 0; cc < 4; cc++) {
            const int icc = cc * 16;
            __syncthreads();
            for (int j = t; j < 1920; j += 320) {
                int ic_l = j / 120; int rem = j % 120;
                int row_l = rem / 20; int c4 = (rem % 20) * 4;
                int gy = gy0 - 1 + row_l;
                float4 v = make_float4(0.f, 0.f, 0.f, 0.f);
                if ((unsigned)gy < 80u)
                    v = *(const float4*)(xin + (size_t)(icc + ic_l) * NPIX + gy * NXX + c4);
                *(float4*)&lxw[(ic_l * 6 + row_l) * 80 + c4] = v;
            }
            for (int j = t; j < 2304; j += 320) {
                int oc_l = j % 16; int k = j / 16;
                int ic_l = k / 9, tap = k % 9;
                lwf[k * 16 + oc_l] =
                    w1[((size_t)(ocg * 16 + oc_l) * CHN + icc + ic_l) * 9 + tap];
            }
            __syncthreads();
            {
                int i0 = cc * 16, i1 = i0 + 16;
                for (int i = i0; i < i1; i++) {
                    long q = (long)gtid + (long)i * nth;
                    if (q < QF1) __builtin_nontemporal_store(fz, outq + q);
                }
            }
            for (int ic = 0; ic < 16; ic++) {
                float xw[3][6];
                #pragma unroll
                for (int ky = 0; ky < 3; ky++) {
                    const float* row = &lxw[(ic * 6 + r + ky) * 80];
                    xw[ky][0] = (c > 0) ? row[c - 1] : 0.f;
                    float4 m = *(const float4*)&row[c];
                    xw[ky][1] = m.x; xw[ky][2] = m.y;
                    xw[ky][3] = m.z; xw[ky][4] = m.w;
                    xw[ky][5] = (c < 76) ? row[c + 4] : 0.f;
                }
                #pragma unroll
                for (int ky = 0; ky < 3; ky++)
                #pragma unroll
                for (int kx = 0; kx < 3; kx++) {
                    const float* wv = &lwf[(ic * 9 + ky * 3 + kx) * 16 + ocq * 4];
                    float w0 = wv[0], w1v = wv[1], w2 = wv[2], w3 = wv[3];
                    #pragma unroll
                    for (int j = 0; j < 4; j++) {
                        float xv = xw[ky][j + kx];
                        acc[j][0] += xv * w0; acc[j][1] += xv * w1v;
                        acc[j][2] += xv * w2; acc[j][3] += xv * w3;
                    }
                }
            }
        }
        size_t pix = (size_t)(gy0 + r) * NXX + c;
        #pragma unroll
        for (int o = 0; o < 4; o++) {
            float4 v;
            v.x = fmaxf(acc[0][o], 0.f); v.y = fmaxf(acc[1][o], 0.f);
            v.z = fmaxf(acc[2][o], 0.f); v.w = fmaxf(acc[3][o], 0.f);
            *(float4*)(c1wr + ((size_t)img * CHN + oc0 + o) * NPIX + pix) = v;
        }
    }
}

// ============ K2a: hm 1x1 conv -> RAW LOGIT, FP64, fetch-once all-oc ============
// grid 200 (b*100 + px-chunk of 64), 256 thr = 64 px x 4 ocg (20 oc each)
__global__ __launch_bounds__(256)
void conv2_hm_kernel(const double* __restrict__ c1,
                     const float* __restrict__ w2,
                     const float* __restrict__ b2,
                     double* __restrict__ hm_z,
                     vf4* __restrict__ outq)
{
    __shared__ double lx[64 * 64];    // [ic][px]  32,768 B
    __shared__ double lw[64 * 80];    // [ic][oc]  40,960 B

    const int bl  = blockIdx.x;
    const int t   = threadIdx.x;
    const int b   = bl / 100;
    const int px0 = (bl % 100) * 64;

    // zero-fill slice (drains under staging+compute)
    {
        const int gtid = bl * 256 + t;
        const vf4 fz = {0.f, 0.f, 0.f, 0.f};
        for (int i = 0; i < 13; i++) {
            long q = QF1 + (long)gtid + (long)i * 51200;
            if (q < QF2) __builtin_nontemporal_store(fz, outq + q);
        }
    }

    const double* in = c1 + (size_t)b * CHN * NPIX;
    for (int j = t; j < 4096; j += 256) {
        int ic = j >> 6, px = j & 63;
        lx[j] = in[(size_t)ic * NPIX + px0 + px];
    }
    for (int j = t; j < 5120; j += 256) {
        int ic = j / 80, oc = j % 80;
        lw[j] = (double)w2[(size_t)oc * CHN + ic];
    }
    __syncthreads();

    const int px  = t & 63;
    const int ocg = t >> 6;            // 0..3 (wave-uniform)
    double acc[20];
    #pragma unroll
    for (int o = 0; o < 20; o++) acc[o] = (double)b2[ocg * 20 + o];

    for (int ic = 0; ic < 64; ic++) {
        double xv = lx[ic * 64 + px];
        const double* wrow = &lw[ic * 80 + ocg * 20];
        #pragma unroll
        for (int o = 0; o < 20; o++) acc[o] += xv * wrow[o];
    }
    #pragma unroll
    for (int o = 0; o < 20; o++)
        hm_z[((size_t)b * NCLS + ocg * 20 + o) * NPIX + px0 + px] = acc[o];
}

// ============ K2b: wh/reg 1x1 conv + relu, FP32 ============
// grid (25, 4, 2)
__global__ __launch_bounds__(256)
void conv2_wr_kernel(const float* __restrict__ c1,
                     const float* __restrict__ wh_w2, const float* __restrict__ wh_b2,
                     const float* __restrict__ rg_w2, const float* __restrict__ rg_b2,
                     float* __restrict__ wh, float* __restrict__ rg)
{
    int p  = blockIdx.x * 256 + threadIdx.x;
    int hc = blockIdx.y;
    int b  = blockIdx.z;
    int head = hc >> 1, ch = hc & 1;

    const float* in = c1 + ((size_t)(head * 2 + b) * CHN) * NPIX;
    const float* w  = (head == 0) ? wh_w2 + (size_t)ch * CHN : rg_w2 + (size_t)ch * CHN;
    float bias      = (head == 0) ? wh_b2[ch] : rg_b2[ch];

    float acc = bias;
    for (int ic = 0; ic < CHN; ic++) acc += in[(size_t)ic * NPIX + p] * w[ic];
    acc = fmaxf(acc, 0.f);
    float* o = (head == 0) ? wh : rg;
    o[((size_t)b * 2 + ch) * NPIX + p] = acc;
}

// ============ K3a: maxima flags on fp64 LOGITS (sigmoid monotone) ============
// grid (500, 2), 1024 thr
__global__ void flags_kernel(const double* __restrict__ hm_z,
                             unsigned long long* __restrict__ ballots,
                             unsigned int* __restrict__ counts,
                             vf4* __restrict__ outq)
{
    int b = blockIdx.y;
    int k = blockIdx.x * 1024 + threadIdx.x;

    // zero-fill slice
    {
        const int gtid = (b * NBLK + blockIdx.x) * 1024 + threadIdx.x;
        const vf4 fz = {0.f, 0.f, 0.f, 0.f};
        for (int i = 0; i < 6; i++) {
            long q = QF2 + (long)gtid + (long)i * 1024000;
            if (q < QF3) __builtin_nontemporal_store(fz, outq + q);
        }
    }

    int c = k / NPIX;
    int p = k - c * NPIX;
    int y = p / NXX, xx = p - y * NXX;

    const double* h = hm_z + ((size_t)b * NCLS + c) * NPIX;
    double s = h[p];
    double m = s;
    #pragma unroll
    for (int dy = -1; dy <= 1; dy++) {
        int yy = y + dy;
        if ((unsigned)yy >= (unsigned)NYY) continue;
        const double* hr = h + yy * NXX;
        #pragma unroll
        for (int dx = -1; dx <= 1; dx++) {
            int xn = xx + dx;
            if ((unsigned)xn >= (unsigned)NXX) continue;
            double v = hr[xn];
            m = v > m ? v : m;
        }
    }
    bool flag = (s == m);
    unsigned long long ball = __ballot(flag);
    int lane = threadIdx.x & 63;
    int wave = threadIdx.x >> 6;

    __shared__ unsigned int wcnt[16];
    if (lane == 0) {
        ballots[(size_t)b * 8000 + blockIdx.x * 16 + wave] = ball;
        wcnt[wave] = __popcll(ball);
    }
    __syncthreads();
    if (threadIdx.x == 0) {
        unsigned int tot = 0;
        for (int i = 0; i < 16; i++) tot += wcnt[i];
        counts[b * NBLK + blockIdx.x] = tot;
    }
}

// ============ K3b: exclusive scan of 500 block counts per batch ============
__global__ void scan_kernel(const unsigned int* __restrict__ counts,
                            unsigned int* __restrict__ offs)
{
    int b = blockIdx.x;
    int t = threadIdx.x;
    unsigned int v = (t < NBLK) ? counts[b * NBLK + t] : 0u;
    unsigned int xi = v;
    #pragma unroll
    for (int d = 1; d < 64; d <<= 1) {
        unsigned int n = __shfl_up(xi, d, 64);
        if ((t & 63) >= d) xi += n;
    }
    __shared__ unsigned int wtot[8];
    __shared__ unsigned int wbase[8];
    if ((t & 63) == 63) wtot[t >> 6] = xi;
    __syncthreads();
    if (t == 0) {
        unsigned int a = 0;
        for (int i = 0; i < 8; i++) { wbase[i] = a; a += wtot[i]; }
    }
    __syncthreads();
    unsigned int excl = xi - v + wbase[t >> 6];
    if (t < NBLK) offs[b * NBLK + t] = excl;
}

// ============ K3c: scatter maxima rows (sigmoid only here) ============
// grid (500, 2), 1024 thr
__global__ void scatter_kernel(const unsigned long long* __restrict__ ballots,
                               const unsigned int* __restrict__ offs,
                               const double* __restrict__ hm_z,
                               const float* __restrict__ wh,
                               const float* __restrict__ rg,
                               const float* __restrict__ offsets,
                               float* __restrict__ out,
                               vf4* __restrict__ outq)
{
    int b = blockIdx.y;
    int k = blockIdx.x * 1024 + threadIdx.x;
    int lane = threadIdx.x & 63;
    int wave = threadIdx.x >> 6;

    // zero-fill tail slice (batch-1 rows >= 409600: never written by rows)
    {
        const int gtid = (b * NBLK + blockIdx.x) * 1024 + threadIdx.x;
        const vf4 fz = {0.f, 0.f, 0.f, 0.f};
        for (int i = 0; i < 3; i++) {
            long q = QF3 + (long)gtid + (long)i * 1024000;
            if (q < QTOT) __builtin_nontemporal_store(fz, outq + q);
        }
    }

    unsigned long long ball = ballots[(size_t)b * 8000 + blockIdx.x * 16 + wave];

    __shared__ unsigned int wc[16];
    __shared__ unsigned int wb[16];
    if (lane == 0) wc[wave] = __popcll(ball);
    __syncthreads();
    if (threadIdx.x == 0) {
        unsigned int a = 0;
        for (int i = 0; i < 16; i++) { wb[i] = a; a += wc[i]; }
    }
    __syncthreads();

    bool flag = (ball >> lane) & 1ull;
    if (!flag) return;

    unsigned int rank = offs[b * NBLK + blockIdx.x] + wb[wave]
                      + (unsigned int)__popcll(ball & ((1ull << lane) - 1ull));

    int c = k / NPIX;
    int p = k - c * NPIX;
    int y = p / NXX, xx = p - y * NXX;

    float offx = offsets[b * 3 + 1];
    float offy = offsets[b * 3 + 2];
    float r0 = rg[((size_t)b * 2 + 0) * NPIX + p];
    float r1 = rg[((size_t)b * 2 + 1) * NPIX + p];
    float w0 = wh[((size_t)b * 2 + 0) * NPIX + p];
    float w1 = wh[((size_t)b * 2 + 1) * NPIX + p];
    double z = hm_z[((size_t)b * NCLS + c) * NPIX + p];
    float s  = (float)(1.0 / (1.0 + exp(-z)));

    float cx = ((float)xx + 2.f * offx + r0) * 4.f;
    float cy = ((float)y  + 2.f * offy + r1) * 4.f;

    float* row = out + ((size_t)b * KTOT + rank) * NOUT;
    row[0] = cx;
    row[1] = cy;
    row[2] = w0 * 4.f;
    row[3] = w1 * 4.f;
    row[4] = s;
    row[5 + c] = 1.f;
}

extern "C" void kernel_launch(void* const* d_in, const int* in_sizes, int n_in,
                              void* d_out, int out_size, void* d_ws, size_t ws_size,
                              hipStream_t stream)
{
    const float* x       = (const float*)d_in[0];
    const float* offsets = (const float*)d_in[1];
    const float* hm_w1   = (const float*)d_in[2];
    const float* hm_b1   = (const float*)d_in[3];
    const float* hm_w2   = (const float*)d_in[4];
    const float* hm_b2   = (const float*)d_in[5];
    const float* wh_w1   = (const float*)d_in[6];
    const float* wh_b1   = (const float*)d_in[7];
    const float* wh_w2   = (const float*)d_in[8];
    const float* wh_b2   = (const float*)d_in[9];
    const float* reg_w1  = (const float*)d_in[10];
    const float* reg_b1  = (const float*)d_in[11];
    const float* reg_w2  = (const float*)d_in[12];
    const float* reg_b2  = (const float*)d_in[13];

    float* out = (float*)d_out;
    vf4* outq  = (vf4*)d_out;

    // workspace layout
    char* wp = (char*)d_ws;
    double* c1hm = (double*)wp;                 wp += (size_t)NBATCH * CHN * NPIX * 8;
    double* hm_z = (double*)wp;                 wp += (size_t)NBATCH * NCLS * NPIX * 8;
    float*  c1wr = (float*)wp;                  wp += (size_t)2 * NBATCH * CHN * NPIX * 4;
    float*  wh   = (float*)wp;                  wp += (size_t)NBATCH * 2 * NPIX * 4;
    float*  rg   = (float*)wp;                  wp += (size_t)NBATCH * 2 * NPIX * 4;
    unsigned long long* ballots = (unsigned long long*)wp; wp += (size_t)NBATCH * 8000 * 8;
    unsigned int* counts = (unsigned int*)wp;   wp += (size_t)NBATCH * NBLK * 4;
    unsigned int* offs   = (unsigned int*)wp;

    conv1_kernel<<<640, 320, 0, stream>>>(
        x, hm_w1, hm_b1, wh_w1, wh_b1, reg_w1, reg_b1, c1hm, c1wr, outq);

    conv2_hm_kernel<<<200, 256, 0, stream>>>(c1hm, hm_w2, hm_b2, hm_z, outq);

    conv2_wr_kernel<<<dim3(25, 4, 2), 256, 0, stream>>>(
        c1wr, wh_w2, wh_b2, reg_w2, reg_b2, wh, rg);

    flags_kernel<<<dim3(NBLK, 2), 1024, 0, stream>>>(hm_z, ballots, counts, outq);

    scan_kernel<<<2, 512, 0, stream>>>(counts, offs);

    scatter_kernel<<<dim3(NBLK, 2), 1024, 0, stream>>>(
        ballots, offs, hm_z, wh, rg, offsets, out, outq);
}

// Round 13
// 151.832 us; speedup vs baseline: 2.7283x; 1.0448x over previous
//
#include <hip/hip_runtime.h>
#include <math.h>

#define NBATCH 2
#define CHN    64
#define NYY    80
#define NXX    80
#define NCLS   80
#define NPIX   6400      // 80*80
#define KTOT   512000    // NCLS*NPIX
#define NOUT   85        // 5 + NCLS
#define NBLK   500       // KTOT / 1024

typedef float vf4 __attribute__((ext_vector_type(4)));

// output = 87,040,000 floats = 21,760,000 float4 quads
#define QTOT   21760000L
#define QF1    11980800L     // conv1: 78 iters x 153600 (55%)
#define QF2    15257600L     // K2 (conv2 merged): 32 iters x 102400 (15%)
#define QF3    20377600L     // flags: 5 x 1024000 (23.5%)
                             // scatter: QF3..QTOT (guarded)

// ============ K1: fused 3x3 conv + ReLU (hm fp64-acc | wh/reg fp32) ============
// grid 480 x 320 thr, 49,152 B LDS -> 3 blocks/CU, fully resident.
// bl%3==0 -> hm block (idx=bl/3, 160 total): 4-row x 80-col tile, 16 oc, fp64 acc.
// else    -> wr block (idx=bl-bl/3-1, 320 total): 4-row x 80-col tile, 16 oc, fp32.
// Interleave spreads the 2x-cost fp64 blocks evenly across XCDs/CUs.
__global__ __launch_bounds__(320)
void conv1_kernel(const float* __restrict__ x,
                  const float* __restrict__ hw1, const float* __restrict__ hb1,
                  const float* __restrict__ ww1, const float* __restrict__ wb1,
                  const float* __restrict__ rw1, const float* __restrict__ rb1,
                  double* __restrict__ c1hm, float* __restrict__ c1wr,
                  vf4* __restrict__ outq)
{
    __shared__ double smem_d[6144];    // 49,152 B
    const int bl = blockIdx.x;
    const int t  = threadIdx.x;

    const int gtid = bl * 320 + t;
    const int nth  = 480 * 320;        // 153600
    const vf4 fz = {0.f, 0.f, 0.f, 0.f};

    // common tile coords: 4 rows x 80 cols, 4 px x 4 oc per thread
    const int pxq = t % 80;
    const int ocq = t / 80;            // 0..3
    const int r   = pxq / 20;          // row 0..3
    const int c   = (pxq % 20) * 4;    // col 0..76

    float* lxf = (float*)smem_d;       // [16][6][80] floats = 30,720 B (aligned, no shift)

    if (bl % 3 == 0) {
        // ---------------- hm path: fp64 acc ----------------
        double* lwd = (double*)((char*)smem_d + 30720);  // [144][16] = 18,432 B

        const int idx = bl / 3;        // 0..159
        const int yt  = idx % 20;
        const int ocg = (idx / 20) % 4;
        const int b   = idx / 80;
        const int oc0 = ocg * 16 + ocq * 4;
        const int gy0 = yt * 4;

        const float* xin = x + (size_t)b * CHN * NPIX;

        double acc[4][4];
        #pragma unroll
        for (int j = 0; j < 4; j++)
            #pragma unroll
            for (int o = 0; o < 4; o++) acc[j][o] = (double)hb1[oc0 + o];

        for (int cc = 0; cc < 4; cc++) {
            const int icc = cc * 16;
            __syncthreads();
            for (int j = t; j < 1920; j += 320) {
                int ic_l = j / 120; int rem = j % 120;
                int row_l = rem / 20; int c4 = (rem % 20) * 4;
                int gy = gy0 - 1 + row_l;
                float4 v = make_float4(0.f, 0.f, 0.f, 0.f);
                if ((unsigned)gy < 80u)
                    v = *(const float4*)(xin + (size_t)(icc + ic_l) * NPIX + gy * NXX + c4);
                *(float4*)&lxf[(ic_l * 6 + row_l) * 80 + c4] = v;   // aligned, conflict-free
            }
            for (int j = t; j < 2304; j += 320) {
                int oc_l = j % 16; int k = j / 16;
                int ic_l = k / 9, tap = k % 9;
                lwd[k * 16 + oc_l] =
                    (double)hw1[((size_t)(ocg * 16 + oc_l) * CHN + icc + ic_l) * 9 + tap];
            }
            __syncthreads();
            {   // zero-fill slice (drains under fp64 compute)
                int i0 = cc * 20, i1 = (cc == 3) ? 78 : cc * 20 + 20;
                for (int i = i0; i < i1; i++) {
                    long q = (long)gtid + (long)i * nth;
                    if (q < QF1) __builtin_nontemporal_store(fz, outq + q);
                }
            }
            for (int ic = 0; ic < 16; ic++) {
                double xw[3][6];
                #pragma unroll
                for (int ky = 0; ky < 3; ky++) {
                    const float* row = &lxf[(ic * 6 + r + ky) * 80];
                    xw[ky][0] = (c > 0) ? (double)row[c - 1] : 0.0;
                    float4 m = *(const float4*)&row[c];
                    xw[ky][1] = (double)m.x; xw[ky][2] = (double)m.y;
                    xw[ky][3] = (double)m.z; xw[ky][4] = (double)m.w;
                    xw[ky][5] = (c < 76) ? (double)row[c + 4] : 0.0;
                }
                #pragma unroll
                for (int ky = 0; ky < 3; ky++)
                #pragma unroll
                for (int kx = 0; kx < 3; kx++) {
                    const double* wv = &lwd[(ic * 9 + ky * 3 + kx) * 16 + ocq * 4];
                    double w0 = wv[0], w1d = wv[1], w2 = wv[2], w3 = wv[3];
                    #pragma unroll
                    for (int j = 0; j < 4; j++) {
                        double xv = xw[ky][j + kx];
                        acc[j][0] += xv * w0; acc[j][1] += xv * w1d;
                        acc[j][2] += xv * w2; acc[j][3] += xv * w3;
                    }
                }
            }
        }
        size_t pix = (size_t)(gy0 + r) * NXX + c;
        #pragma unroll
        for (int o = 0; o < 4; o++) {
            double* dst = c1hm + ((size_t)b * CHN + oc0 + o) * NPIX + pix;
            double2 lo, hi;
            lo.x = acc[0][o] > 0.0 ? acc[0][o] : 0.0;
            lo.y = acc[1][o] > 0.0 ? acc[1][o] : 0.0;
            hi.x = acc[2][o] > 0.0 ? acc[2][o] : 0.0;
            hi.y = acc[3][o] > 0.0 ? acc[3][o] : 0.0;
            *(double2*)dst = lo;
            *(double2*)(dst + 2) = hi;
        }
    } else {
        // ---------------- wh/reg path: fp32 ----------------
        float* lwf = (float*)((char*)smem_d + 30720);    // [144][16] = 9,216 B

        const int idx = bl - bl / 3 - 1;   // 0..319
        const int yt  = idx % 20;
        const int ocg = (idx / 20) % 4;
        const int img = idx / 80;          // 0=wh b0, 1=wh b1, 2=reg b0, 3=reg b1

        const int head = img >> 1, b = img & 1;
        const float* w1 = (head == 0) ? ww1 : rw1;
        const float* b1 = (head == 0) ? wb1 : rb1;
        const float* xin = x + (size_t)b * CHN * NPIX;

        const int oc0 = ocg * 16 + ocq * 4;
        const int gy0 = yt * 4;

        float acc[4][4];
        #pragma unroll
        for (int j = 0; j < 4; j++)
            #pragma unroll
            for (int o = 0; o < 4; o++) acc[j][o] = b1[oc0 + o];

        for (int cc = 0; cc < 4; cc++) {
            const int icc = cc * 16;
            __syncthreads();
            for (int j = t; j < 1920; j += 320) {
                int ic_l = j / 120; int rem = j % 120;
                int row_l = rem / 20; int c4 = (rem % 20) * 4;
                int gy = gy0 - 1 + row_l;
                float4 v = make_float4(0.f, 0.f, 0.f, 0.f);
                if ((unsigned)gy < 80u)
                    v = *(const float4*)(xin + (size_t)(icc + ic_l) * NPIX + gy * NXX + c4);
                *(float4*)&lxf[(ic_l * 6 + row_l) * 80 + c4] = v;
            }
            for (int j = t; j < 2304; j += 320) {
                int oc_l = j % 16; int k = j / 16;
                int ic_l = k / 9, tap = k % 9;
                lwf[k * 16 + oc_l] =
                    w1[((size_t)(ocg * 16 + oc_l) * CHN + icc + ic_l) * 9 + tap];
            }
            __syncthreads();
            {
                int i0 = cc * 20, i1 = (cc == 3) ? 78 : cc * 20 + 20;
                for (int i = i0; i < i1; i++) {
                    long q = (long)gtid + (long)i * nth;
                    if (q < QF1) __builtin_nontemporal_store(fz, outq + q);
                }
            }
            for (int ic = 0; ic < 16; ic++) {
                float xw[3][6];
                #pragma unroll
                for (int ky = 0; ky < 3; ky++) {
                    const float* row = &lxf[(ic * 6 + r + ky) * 80];
                    xw[ky][0] = (c > 0) ? row[c - 1] : 0.f;
                    float4 m = *(const float4*)&row[c];
                    xw[ky][1] = m.x; xw[ky][2] = m.y;
                    xw[ky][3] = m.z; xw[ky][4] = m.w;
                    xw[ky][5] = (c < 76) ? row[c + 4] : 0.f;
                }
                #pragma unroll
                for (int ky = 0; ky < 3; ky++)
                #pragma unroll
                for (int kx = 0; kx < 3; kx++) {
                    const float* wv = &lwf[(ic * 9 + ky * 3 + kx) * 16 + ocq * 4];
                    float w0 = wv[0], w1v = wv[1], w2 = wv[2], w3 = wv[3];
                    #pragma unroll
                    for (int j = 0; j < 4; j++) {
                        float xv = xw[ky][j + kx];
                        acc[j][0] += xv * w0; acc[j][1] += xv * w1v;
                        acc[j][2] += xv * w2; acc[j][3] += xv * w3;
                    }
                }
            }
        }
        size_t pix = (size_t)(gy0 + r) * NXX + c;
        #pragma unroll
        for (int o = 0; o < 4; o++) {
            float4 v;
            v.x = fmaxf(acc[0][o], 0.f); v.y = fmaxf(acc[1][o], 0.f);
            v.z = fmaxf(acc[2][o], 0.f); v.w = fmaxf(acc[3][o], 0.f);
            *(float4*)(c1wr + ((size_t)img * CHN + oc0 + o) * NPIX + pix) = v;
        }
    }
}

// ============ K2: merged conv2_hm (fp64 logits, fetch-once) + conv2_wr ============
// grid 400 x 256 thr. bl<200: hm (b=bl/100, px-chunk of 64, all 80 oc, 20/thread).
//                     bl>=200: wr (blw: chunk=blw%25, hc=(blw/25)%4, b=blw/100).
__global__ __launch_bounds__(256)
void conv2_kernel(const double* __restrict__ c1hm,
                  const float* __restrict__ hm_w2, const float* __restrict__ hm_b2,
                  const float* __restrict__ c1wr,
                  const float* __restrict__ wh_w2, const float* __restrict__ wh_b2,
                  const float* __restrict__ rg_w2, const float* __restrict__ rg_b2,
                  double* __restrict__ hm_z, float* __restrict__ wh, float* __restrict__ rg,
                  vf4* __restrict__ outq)
{
    __shared__ double smem2[9216];     // 73,728 B (hm path only)
    const int bl = blockIdx.x;
    const int t  = threadIdx.x;

    // zero-fill slice (drains under compute)
    {
        const int gtid = bl * 256 + t;
        const vf4 fz = {0.f, 0.f, 0.f, 0.f};
        for (int i = 0; i < 32; i++) {
            long q = QF1 + (long)gtid + (long)i * 102400;
            if (q < QF2) __builtin_nontemporal_store(fz, outq + q);
        }
    }

    if (bl < 200) {
        double* lx = smem2;            // [64 ic][64 px] = 32,768 B
        double* lw = smem2 + 4096;     // [64 ic][80 oc] = 40,960 B

        const int b   = bl / 100;
        const int px0 = (bl % 100) * 64;

        const double* in = c1hm + (size_t)b * CHN * NPIX;
        for (int j = t; j < 4096; j += 256) {
            int ic = j >> 6, px = j & 63;
            lx[j] = in[(size_t)ic * NPIX + px0 + px];
        }
        for (int j = t; j < 5120; j += 256) {
            int ic = j / 80, oc = j % 80;
            lw[j] = (double)hm_w2[(size_t)oc * CHN + ic];
        }
        __syncthreads();

        const int px  = t & 63;
        const int ocg = t >> 6;        // 0..3
        double acc[20];
        #pragma unroll
        for (int o = 0; o < 20; o++) acc[o] = (double)hm_b2[ocg * 20 + o];

        for (int ic = 0; ic < 64; ic++) {
            double xv = lx[ic * 64 + px];
            const double* wrow = &lw[ic * 80 + ocg * 20];
            #pragma unroll
            for (int o = 0; o < 20; o++) acc[o] += xv * wrow[o];
        }
        #pragma unroll
        for (int o = 0; o < 20; o++)
            hm_z[((size_t)b * NCLS + ocg * 20 + o) * NPIX + px0 + px] = acc[o];
    } else {
        const int blw  = bl - 200;
        const int chunk = blw % 25;
        const int hc   = (blw / 25) % 4;
        const int b    = blw / 100;
        const int head = hc >> 1, ch = hc & 1;

        const int p = chunk * 256 + t;
        const float* in = c1wr + ((size_t)(head * 2 + b) * CHN) * NPIX;
        const float* w  = (head == 0) ? wh_w2 + (size_t)ch * CHN : rg_w2 + (size_t)ch * CHN;
        float acc = (head == 0) ? wh_b2[ch] : rg_b2[ch];
        for (int ic = 0; ic < CHN; ic++) acc += in[(size_t)ic * NPIX + p] * w[ic];
        acc = fmaxf(acc, 0.f);
        float* o = (head == 0) ? wh : rg;
        o[((size_t)b * 2 + ch) * NPIX + p] = acc;
    }
}

// ============ K3a: maxima flags on fp64 LOGITS (sigmoid monotone) ============
// grid (500, 2), 1024 thr
__global__ void flags_kernel(const double* __restrict__ hm_z,
                             unsigned long long* __restrict__ ballots,
                             unsigned int* __restrict__ counts,
                             vf4* __restrict__ outq)
{
    int b = blockIdx.y;
    int k = blockIdx.x * 1024 + threadIdx.x;

    // zero-fill slice
    {
        const int gtid = (b * NBLK + blockIdx.x) * 1024 + threadIdx.x;
        const vf4 fz = {0.f, 0.f, 0.f, 0.f};
        for (int i = 0; i < 5; i++) {
            long q = QF2 + (long)gtid + (long)i * 1024000;
            if (q < QF3) __builtin_nontemporal_store(fz, outq + q);
        }
    }

    int c = k / NPIX;
    int p = k - c * NPIX;
    int y = p / NXX, xx = p - y * NXX;

    const double* h = hm_z + ((size_t)b * NCLS + c) * NPIX;
    double s = h[p];
    double m = s;
    #pragma unroll
    for (int dy = -1; dy <= 1; dy++) {
        int yy = y + dy;
        if ((unsigned)yy >= (unsigned)NYY) continue;
        const double* hr = h + yy * NXX;
        #pragma unroll
        for (int dx = -1; dx <= 1; dx++) {
            int xn = xx + dx;
            if ((unsigned)xn >= (unsigned)NXX) continue;
            double v = hr[xn];
            m = v > m ? v : m;
        }
    }
    bool flag = (s == m);
    unsigned long long ball = __ballot(flag);
    int lane = threadIdx.x & 63;
    int wave = threadIdx.x >> 6;

    __shared__ unsigned int wcnt[16];
    if (lane == 0) {
        ballots[(size_t)b * 8000 + blockIdx.x * 16 + wave] = ball;
        wcnt[wave] = __popcll(ball);
    }
    __syncthreads();
    if (threadIdx.x == 0) {
        unsigned int tot = 0;
        for (int i = 0; i < 16; i++) tot += wcnt[i];
        counts[b * NBLK + blockIdx.x] = tot;
    }
}

// ============ K3b: exclusive scan of 500 block counts per batch ============
__global__ void scan_kernel(const unsigned int* __restrict__ counts,
                            unsigned int* __restrict__ offs)
{
    int b = blockIdx.x;
    int t = threadIdx.x;
    unsigned int v = (t < NBLK) ? counts[b * NBLK + t] : 0u;
    unsigned int xi = v;
    #pragma unroll
    for (int d = 1; d < 64; d <<= 1) {
        unsigned int n = __shfl_up(xi, d, 64);
        if ((t & 63) >= d) xi += n;
    }
    __shared__ unsigned int wtot[8];
    __shared__ unsigned int wbase[8];
    if ((t & 63) == 63) wtot[t >> 6] = xi;
    __syncthreads();
    if (t == 0) {
        unsigned int a = 0;
        for (int i = 0; i < 8; i++) { wbase[i] = a; a += wtot[i]; }
    }
    __syncthreads();
    unsigned int excl = xi - v + wbase[t >> 6];
    if (t < NBLK) offs[b * NBLK + t] = excl;
}

// ============ K3c: scatter maxima rows (sigmoid only here) ============
// grid (500, 2), 1024 thr
__global__ void scatter_kernel(const unsigned long long* __restrict__ ballots,
                               const unsigned int* __restrict__ offs,
                               const double* __restrict__ hm_z,
                               const float* __restrict__ wh,
                               const float* __restrict__ rg,
                               const float* __restrict__ offsets,
                               float* __restrict__ out,
                               vf4* __restrict__ outq)
{
    int b = blockIdx.y;
    int k = blockIdx.x * 1024 + threadIdx.x;
    int lane = threadIdx.x & 63;
    int wave = threadIdx.x >> 6;

    // zero-fill tail slice (batch-1 ranks >= ~447K: never written by rows)
    {
        const int gtid = (b * NBLK + blockIdx.x) * 1024 + threadIdx.x;
        const vf4 fz = {0.f, 0.f, 0.f, 0.f};
        for (int i = 0; i < 2; i++) {
            long q = QF3 + (long)gtid + (long)i * 1024000;
            if (q < QTOT) __builtin_nontemporal_store(fz, outq + q);
        }
    }

    unsigned long long ball = ballots[(size_t)b * 8000 + blockIdx.x * 16 + wave];

    __shared__ unsigned int wc[16];
    __shared__ unsigned int wb[16];
    if (lane == 0) wc[wave] = __popcll(ball);
    __syncthreads();
    if (threadIdx.x == 0) {
        unsigned int a = 0;
        for (int i = 0; i < 16; i++) { wb[i] = a; a += wc[i]; }
    }
    __syncthreads();

    bool flag = (ball >> lane) & 1ull;
    if (!flag) return;

    unsigned int rank = offs[b * NBLK + blockIdx.x] + wb[wave]
                      + (unsigned int)__popcll(ball & ((1ull << lane) - 1ull));

    int c = k / NPIX;
    int p = k - c * NPIX;
    int y = p / NXX, xx = p - y * NXX;

    float offx = offsets[b * 3 + 1];
    float offy = offsets[b * 3 + 2];
    float r0 = rg[((size_t)b * 2 + 0) * NPIX + p];
    float r1 = rg[((size_t)b * 2 + 1) * NPIX + p];
    float w0 = wh[((size_t)b * 2 + 0) * NPIX + p];
    float w1 = wh[((size_t)b * 2 + 1) * NPIX + p];
    double z = hm_z[((size_t)b * NCLS + c) * NPIX + p];
    float s  = (float)(1.0 / (1.0 + exp(-z)));

    float cx = ((float)xx + 2.f * offx + r0) * 4.f;
    float cy = ((float)y  + 2.f * offy + r1) * 4.f;

    float* row = out + ((size_t)b * KTOT + rank) * NOUT;
    row[0] = cx;
    row[1] = cy;
    row[2] = w0 * 4.f;
    row[3] = w1 * 4.f;
    row[4] = s;
    row[5 + c] = 1.f;
}

extern "C" void kernel_launch(void* const* d_in, const int* in_sizes, int n_in,
                              void* d_out, int out_size, void* d_ws, size_t ws_size,
                              hipStream_t stream)
{
    const float* x       = (const float*)d_in[0];
    const float* offsets = (const float*)d_in[1];
    const float* hm_w1   = (const float*)d_in[2];
    const float* hm_b1   = (const float*)d_in[3];
    const float* hm_w2   = (const float*)d_in[4];
    const float* hm_b2   = (const float*)d_in[5];
    const float* wh_w1   = (const float*)d_in[6];
    const float* wh_b1   = (const float*)d_in[7];
    const float* wh_w2   = (const float*)d_in[8];
    const float* wh_b2   = (const float*)d_in[9];
    const float* reg_w1  = (const float*)d_in[10];
    const float* reg_b1  = (const float*)d_in[11];
    const float* reg_w2  = (const float*)d_in[12];
    const float* reg_b2  = (const float*)d_in[13];

    float* out = (float*)d_out;
    vf4* outq  = (vf4*)d_out;

    // workspace layout
    char* wp = (char*)d_ws;
    double* c1hm = (double*)wp;                 wp += (size_t)NBATCH * CHN * NPIX * 8;
    double* hm_z = (double*)wp;                 wp += (size_t)NBATCH * NCLS * NPIX * 8;
    float*  c1wr = (float*)wp;                  wp += (size_t)2 * NBATCH * CHN * NPIX * 4;
    float*  wh   = (float*)wp;                  wp += (size_t)NBATCH * 2 * NPIX * 4;
    float*  rg   = (float*)wp;                  wp += (size_t)NBATCH * 2 * NPIX * 4;
    unsigned long long* ballots = (unsigned long long*)wp; wp += (size_t)NBATCH * 8000 * 8;
    unsigned int* counts = (unsigned int*)wp;   wp += (size_t)NBATCH * NBLK * 4;
    unsigned int* offs   = (unsigned int*)wp;

    conv1_kernel<<<480, 320, 0, stream>>>(
        x, hm_w1, hm_b1, wh_w1, wh_b1, reg_w1, reg_b1, c1hm, c1wr, outq);

    conv2_kernel<<<400, 256, 0, stream>>>(
        c1hm, hm_w2, hm_b2, c1wr, wh_w2, wh_b2, reg_w2, reg_b2,
        hm_z, wh, rg, outq);

    flags_kernel<<<dim3(NBLK, 2), 1024, 0, stream>>>(hm_z, ballots, counts, outq);

    scan_kernel<<<2, 512, 0, stream>>>(counts, offs);

    scatter_kernel<<<dim3(NBLK, 2), 1024, 0, stream>>>(
        ballots, offs, hm_z, wh, rg, offsets, out, outq);
}

// Round 14
// 148.520 us; speedup vs baseline: 2.7892x; 1.0223x over previous
//
#include <hip/hip_runtime.h>
#include <math.h>

#define NBATCH 2
#define CHN    64
#define NYY    80
#define NXX    80
#define NCLS   80
#define NPIX   6400      // 80*80
#define KTOT   512000    // NCLS*NPIX
#define NOUT   85        // 5 + NCLS
#define NBLK   500       // KTOT / 1024

typedef float vf4 __attribute__((ext_vector_type(4)));

// output = 87,040,000 floats = 21,760,000 float4 quads
#define QTOT   21760000L
#define QF1    14131200L     // conv1: 92 iters x 153600 (65%)
#define QF2    18534400L     // conv2: 43 iters x 102400 (20%)
                             // flags: QF2..QTOT (4 x 1024000, guarded)

// ============ K1: fused 3x3 conv + ReLU (hm fp64-acc | wh/reg fp32) ============
// grid 480 x 320 thr, 49,152 B LDS. bl%3==0 -> hm (fp64), else wr (fp32).
__global__ __launch_bounds__(320)
void conv1_kernel(const float* __restrict__ x,
                  const float* __restrict__ hw1, const float* __restrict__ hb1,
                  const float* __restrict__ ww1, const float* __restrict__ wb1,
                  const float* __restrict__ rw1, const float* __restrict__ rb1,
                  double* __restrict__ c1hm, float* __restrict__ c1wr,
                  vf4* __restrict__ outq)
{
    __shared__ double smem_d[6144];    // 49,152 B
    const int bl = blockIdx.x;
    const int t  = threadIdx.x;

    const int gtid = bl * 320 + t;
    const int nth  = 480 * 320;        // 153600
    const vf4 fz = {0.f, 0.f, 0.f, 0.f};

    const int pxq = t % 80;
    const int ocq = t / 80;            // 0..3
    const int r   = pxq / 20;          // row 0..3
    const int c   = (pxq % 20) * 4;    // col 0..76

    float* lxf = (float*)smem_d;       // [16][6][80] floats = 30,720 B

    if (bl % 3 == 0) {
        // ---------------- hm path: fp64 acc ----------------
        double* lwd = (double*)((char*)smem_d + 30720);  // [144][16] = 18,432 B

        const int idx = bl / 3;        // 0..159
        const int yt  = idx % 20;
        const int ocg = (idx / 20) % 4;
        const int b   = idx / 80;
        const int oc0 = ocg * 16 + ocq * 4;
        const int gy0 = yt * 4;

        const float* xin = x + (size_t)b * CHN * NPIX;

        double acc[4][4];
        #pragma unroll
        for (int j = 0; j < 4; j++)
            #pragma unroll
            for (int o = 0; o < 4; o++) acc[j][o] = (double)hb1[oc0 + o];

        for (int cc = 0; cc < 4; cc++) {
            const int icc = cc * 16;
            __syncthreads();
            for (int j = t; j < 1920; j += 320) {
                int ic_l = j / 120; int rem = j % 120;
                int row_l = rem / 20; int c4 = (rem % 20) * 4;
                int gy = gy0 - 1 + row_l;
                float4 v = make_float4(0.f, 0.f, 0.f, 0.f);
                if ((unsigned)gy < 80u)
                    v = *(const float4*)(xin + (size_t)(icc + ic_l) * NPIX + gy * NXX + c4);
                *(float4*)&lxf[(ic_l * 6 + row_l) * 80 + c4] = v;
            }
            for (int j = t; j < 2304; j += 320) {
                int oc_l = j % 16; int k = j / 16;
                int ic_l = k / 9, tap = k % 9;
                lwd[k * 16 + oc_l] =
                    (double)hw1[((size_t)(ocg * 16 + oc_l) * CHN + icc + ic_l) * 9 + tap];
            }
            __syncthreads();
            {   // zero-fill slice: 23 iters per phase (92 total)
                int i0 = cc * 23, i1 = i0 + 23;
                for (int i = i0; i < i1; i++) {
                    long q = (long)gtid + (long)i * nth;
                    if (q < QF1) __builtin_nontemporal_store(fz, outq + q);
                }
            }
            for (int ic = 0; ic < 16; ic++) {
                double xw[3][6];
                #pragma unroll
                for (int ky = 0; ky < 3; ky++) {
                    const float* row = &lxf[(ic * 6 + r + ky) * 80];
                    xw[ky][0] = (c > 0) ? (double)row[c - 1] : 0.0;
                    float4 m = *(const float4*)&row[c];
                    xw[ky][1] = (double)m.x; xw[ky][2] = (double)m.y;
                    xw[ky][3] = (double)m.z; xw[ky][4] = (double)m.w;
                    xw[ky][5] = (c < 76) ? (double)row[c + 4] : 0.0;
                }
                #pragma unroll
                for (int ky = 0; ky < 3; ky++)
                #pragma unroll
                for (int kx = 0; kx < 3; kx++) {
                    const double* wv = &lwd[(ic * 9 + ky * 3 + kx) * 16 + ocq * 4];
                    double w0 = wv[0], w1d = wv[1], w2 = wv[2], w3 = wv[3];
                    #pragma unroll
                    for (int j = 0; j < 4; j++) {
                        double xv = xw[ky][j + kx];
                        acc[j][0] += xv * w0; acc[j][1] += xv * w1d;
                        acc[j][2] += xv * w2; acc[j][3] += xv * w3;
                    }
                }
            }
        }
        size_t pix = (size_t)(gy0 + r) * NXX + c;
        #pragma unroll
        for (int o = 0; o < 4; o++) {
            double* dst = c1hm + ((size_t)b * CHN + oc0 + o) * NPIX + pix;
            double2 lo, hi;
            lo.x = acc[0][o] > 0.0 ? acc[0][o] : 0.0;
            lo.y = acc[1][o] > 0.0 ? acc[1][o] : 0.0;
            hi.x = acc[2][o] > 0.0 ? acc[2][o] : 0.0;
            hi.y = acc[3][o] > 0.0 ? acc[3][o] : 0.0;
            *(double2*)dst = lo;
            *(double2*)(dst + 2) = hi;
        }
    } else {
        // ---------------- wh/reg path: fp32 ----------------
        float* lwf = (float*)((char*)smem_d + 30720);    // [144][16] = 9,216 B

        const int idx = bl - bl / 3 - 1;   // 0..319
        const int yt  = idx % 20;
        const int ocg = (idx / 20) % 4;
        const int img = idx / 80;          // 0=wh b0, 1=wh b1, 2=reg b0, 3=reg b1

        const int head = img >> 1, b = img & 1;
        const float* w1 = (head == 0) ? ww1 : rw1;
        const float* b1 = (head == 0) ? wb1 : rb1;
        const float* xin = x + (size_t)b * CHN * NPIX;

        const int oc0 = ocg * 16 + ocq * 4;
        const int gy0 = yt * 4;

        float acc[4][4];
        #pragma unroll
        for (int j = 0; j < 4; j++)
            #pragma unroll
            for (int o = 0; o < 4; o++) acc[j][o] = b1[oc0 + o];

        for (int cc = 0; cc < 4; cc++) {
            const int icc = cc * 16;
            __syncthreads();
            for (int j = t; j < 1920; j += 320) {
                int ic_l = j / 120; int rem = j % 120;
                int row_l = rem / 20; int c4 = (rem % 20) * 4;
                int gy = gy0 - 1 + row_l;
                float4 v = make_float4(0.f, 0.f, 0.f, 0.f);
                if ((unsigned)gy < 80u)
                    v = *(const float4*)(xin + (size_t)(icc + ic_l) * NPIX + gy * NXX + c4);
                *(float4*)&lxf[(ic_l * 6 + row_l) * 80 + c4] = v;
            }
            for (int j = t; j < 2304; j += 320) {
                int oc_l = j % 16; int k = j / 16;
                int ic_l = k / 9, tap = k % 9;
                lwf[k * 16 + oc_l] =
                    w1[((size_t)(ocg * 16 + oc_l) * CHN + icc + ic_l) * 9 + tap];
            }
            __syncthreads();
            {
                int i0 = cc * 23, i1 = i0 + 23;
                for (int i = i0; i < i1; i++) {
                    long q = (long)gtid + (long)i * nth;
                    if (q < QF1) __builtin_nontemporal_store(fz, outq + q);
                }
            }
            for (int ic = 0; ic < 16; ic++) {
                float xw[3][6];
                #pragma unroll
                for (int ky = 0; ky < 3; ky++) {
                    const float* row = &lxf[(ic * 6 + r + ky) * 80];
                    xw[ky][0] = (c > 0) ? row[c - 1] : 0.f;
                    float4 m = *(const float4*)&row[c];
                    xw[ky][1] = m.x; xw[ky][2] = m.y;
                    xw[ky][3] = m.z; xw[ky][4] = m.w;
                    xw[ky][5] = (c < 76) ? row[c + 4] : 0.f;
                }
                #pragma unroll
                for (int ky = 0; ky < 3; ky++)
                #pragma unroll
                for (int kx = 0; kx < 3; kx++) {
                    const float* wv = &lwf[(ic * 9 + ky * 3 + kx) * 16 + ocq * 4];
                    float w0 = wv[0], w1v = wv[1], w2 = wv[2], w3 = wv[3];
                    #pragma unroll
                    for (int j = 0; j < 4; j++) {
                        float xv = xw[ky][j + kx];
                        acc[j][0] += xv * w0; acc[j][1] += xv * w1v;
                        acc[j][2] += xv * w2; acc[j][3] += xv * w3;
                    }
                }
            }
        }
        size_t pix = (size_t)(gy0 + r) * NXX + c;
        #pragma unroll
        for (int o = 0; o < 4; o++) {
            float4 v;
            v.x = fmaxf(acc[0][o], 0.f); v.y = fmaxf(acc[1][o], 0.f);
            v.z = fmaxf(acc[2][o], 0.f); v.w = fmaxf(acc[3][o], 0.f);
            *(float4*)(c1wr + ((size_t)img * CHN + oc0 + o) * NPIX + pix) = v;
        }
    }
}

// ============ K2: merged conv2_hm (fp64 logits, fetch-once) + conv2_wr ============
// grid 400 x 256 thr. bl<200: hm. bl>=200: wr.
__global__ __launch_bounds__(256)
void conv2_kernel(const double* __restrict__ c1hm,
                  const float* __restrict__ hm_w2, const float* __restrict__ hm_b2,
                  const float* __restrict__ c1wr,
                  const float* __restrict__ wh_w2, const float* __restrict__ wh_b2,
                  const float* __restrict__ rg_w2, const float* __restrict__ rg_b2,
                  double* __restrict__ hm_z, float* __restrict__ wh, float* __restrict__ rg,
                  vf4* __restrict__ outq)
{
    __shared__ double smem2[9216];     // 73,728 B (hm path only)
    const int bl = blockIdx.x;
    const int t  = threadIdx.x;

    // zero-fill slice (drains under compute)
    {
        const int gtid = bl * 256 + t;
        const vf4 fz = {0.f, 0.f, 0.f, 0.f};
        for (int i = 0; i < 43; i++) {
            long q = QF1 + (long)gtid + (long)i * 102400;
            if (q < QF2) __builtin_nontemporal_store(fz, outq + q);
        }
    }

    if (bl < 200) {
        double* lx = smem2;            // [64 ic][64 px] = 32,768 B
        double* lw = smem2 + 4096;     // [64 ic][80 oc] = 40,960 B

        const int b   = bl / 100;
        const int px0 = (bl % 100) * 64;

        const double* in = c1hm + (size_t)b * CHN * NPIX;
        for (int j = t; j < 4096; j += 256) {
            int ic = j >> 6, px = j & 63;
            lx[j] = in[(size_t)ic * NPIX + px0 + px];
        }
        for (int j = t; j < 5120; j += 256) {
            int ic = j / 80, oc = j % 80;
            lw[j] = (double)hm_w2[(size_t)oc * CHN + ic];
        }
        __syncthreads();

        const int px  = t & 63;
        const int ocg = t >> 6;        // 0..3 (wave-uniform -> broadcast reads)
        double acc[20];
        #pragma unroll
        for (int o = 0; o < 20; o++) acc[o] = (double)hm_b2[ocg * 20 + o];

        for (int ic = 0; ic < 64; ic++) {
            double xv = lx[ic * 64 + px];
            const double* wrow = &lw[ic * 80 + ocg * 20];
            #pragma unroll
            for (int o = 0; o < 20; o++) acc[o] += xv * wrow[o];
        }
        #pragma unroll
        for (int o = 0; o < 20; o++)
            hm_z[((size_t)b * NCLS + ocg * 20 + o) * NPIX + px0 + px] = acc[o];
    } else {
        const int blw  = bl - 200;
        const int chunk = blw % 25;
        const int hc   = (blw / 25) % 4;
        const int b    = blw / 100;
        const int head = hc >> 1, ch = hc & 1;

        const int p = chunk * 256 + t;
        const float* in = c1wr + ((size_t)(head * 2 + b) * CHN) * NPIX;
        const float* w  = (head == 0) ? wh_w2 + (size_t)ch * CHN : rg_w2 + (size_t)ch * CHN;
        float acc = (head == 0) ? wh_b2[ch] : rg_b2[ch];
        for (int ic = 0; ic < CHN; ic++) acc += in[(size_t)ic * NPIX + p] * w[ic];
        acc = fmaxf(acc, 0.f);
        float* o = (head == 0) ? wh : rg;
        o[((size_t)b * 2 + ch) * NPIX + p] = acc;
    }
}

// ============ K3: maxima flags on fp64 LOGITS (sigmoid monotone) ============
// grid (500, 2), 1024 thr
__global__ void flags_kernel(const double* __restrict__ hm_z,
                             unsigned long long* __restrict__ ballots,
                             unsigned int* __restrict__ counts,
                             vf4* __restrict__ outq)
{
    int b = blockIdx.y;
    int k = blockIdx.x * 1024 + threadIdx.x;

    // zero-fill slice (covers QF2..QTOT, guarded)
    {
        const int gtid = (b * NBLK + blockIdx.x) * 1024 + threadIdx.x;
        const vf4 fz = {0.f, 0.f, 0.f, 0.f};
        for (int i = 0; i < 4; i++) {
            long q = QF2 + (long)gtid + (long)i * 1024000;
            if (q < QTOT) __builtin_nontemporal_store(fz, outq + q);
        }
    }

    int c = k / NPIX;
    int p = k - c * NPIX;
    int y = p / NXX, xx = p - y * NXX;

    const double* h = hm_z + ((size_t)b * NCLS + c) * NPIX;
    double s = h[p];
    double m = s;
    #pragma unroll
    for (int dy = -1; dy <= 1; dy++) {
        int yy = y + dy;
        if ((unsigned)yy >= (unsigned)NYY) continue;
        const double* hr = h + yy * NXX;
        #pragma unroll
        for (int dx = -1; dx <= 1; dx++) {
            int xn = xx + dx;
            if ((unsigned)xn >= (unsigned)NXX) continue;
            double v = hr[xn];
            m = v > m ? v : m;
        }
    }
    bool flag = (s == m);
    unsigned long long ball = __ballot(flag);
    int lane = threadIdx.x & 63;
    int wave = threadIdx.x >> 6;

    __shared__ unsigned int wcnt[16];
    if (lane == 0) {
        ballots[(size_t)b * 8000 + blockIdx.x * 16 + wave] = ball;
        wcnt[wave] = __popcll(ball);
    }
    __syncthreads();
    if (threadIdx.x == 0) {
        unsigned int tot = 0;
        for (int i = 0; i < 16; i++) tot += wcnt[i];
        counts[b * NBLK + blockIdx.x] = tot;
    }
}

// ============ K4: scatter maxima rows (inline cross-block offset, sigmoid) ============
// grid (500, 2), 1024 thr
__global__ void scatter_kernel(const unsigned long long* __restrict__ ballots,
                               const unsigned int* __restrict__ counts,
                               const double* __restrict__ hm_z,
                               const float* __restrict__ wh,
                               const float* __restrict__ rg,
                               const float* __restrict__ offsets,
                               float* __restrict__ out)
{
    __shared__ unsigned int csum[512];
    __shared__ unsigned int wc[16];
    __shared__ unsigned int wb[16];
    __shared__ unsigned int sbase;

    int b  = blockIdx.y;
    int bx = blockIdx.x;
    int t  = threadIdx.x;
    int lane = t & 63;
    int wave = t >> 6;

    if (t < 512) csum[t] = (t < NBLK) ? counts[b * NBLK + t] : 0u;

    unsigned long long ball = ballots[(size_t)b * 8000 + bx * 16 + wave];
    if (lane == 0) wc[wave] = __popcll(ball);
    __syncthreads();

    // cross-block exclusive offset: sum of counts[0..bx-1] via one wave
    if (t < 64) {
        unsigned int s = 0;
        for (int j = t; j < bx; j += 64) s += csum[j];
        #pragma unroll
        for (int d = 32; d >= 1; d >>= 1) s += __shfl_xor(s, d, 64);
        if (t == 0) {
            sbase = s;
            unsigned int a = 0;
            for (int i = 0; i < 16; i++) { wb[i] = a; a += wc[i]; }
        }
    }
    __syncthreads();

    bool flag = (ball >> lane) & 1ull;
    if (!flag) return;

    unsigned int rank = sbase + wb[wave]
                      + (unsigned int)__popcll(ball & ((1ull << lane) - 1ull));

    int k = bx * 1024 + t;
    int c = k / NPIX;
    int p = k - c * NPIX;
    int y = p / NXX, xx = p - y * NXX;

    float offx = offsets[b * 3 + 1];
    float offy = offsets[b * 3 + 2];
    float r0 = rg[((size_t)b * 2 + 0) * NPIX + p];
    float r1 = rg[((size_t)b * 2 + 1) * NPIX + p];
    float w0 = wh[((size_t)b * 2 + 0) * NPIX + p];
    float w1 = wh[((size_t)b * 2 + 1) * NPIX + p];
    double z = hm_z[((size_t)b * NCLS + c) * NPIX + p];
    float s  = (float)(1.0 / (1.0 + exp(-z)));

    float cx = ((float)xx + 2.f * offx + r0) * 4.f;
    float cy = ((float)y  + 2.f * offy + r1) * 4.f;

    float* row = out + ((size_t)b * KTOT + rank) * NOUT;
    row[0] = cx;
    row[1] = cy;
    row[2] = w0 * 4.f;
    row[3] = w1 * 4.f;
    row[4] = s;
    row[5 + c] = 1.f;
}

extern "C" void kernel_launch(void* const* d_in, const int* in_sizes, int n_in,
                              void* d_out, int out_size, void* d_ws, size_t ws_size,
                              hipStream_t stream)
{
    const float* x       = (const float*)d_in[0];
    const float* offsets = (const float*)d_in[1];
    const float* hm_w1   = (const float*)d_in[2];
    const float* hm_b1   = (const float*)d_in[3];
    const float* hm_w2   = (const float*)d_in[4];
    const float* hm_b2   = (const float*)d_in[5];
    const float* wh_w1   = (const float*)d_in[6];
    const float* wh_b1   = (const float*)d_in[7];
    const float* wh_w2   = (const float*)d_in[8];
    const float* wh_b2   = (const float*)d_in[9];
    const float* reg_w1  = (const float*)d_in[10];
    const float* reg_b1  = (const float*)d_in[11];
    const float* reg_w2  = (const float*)d_in[12];
    const float* reg_b2  = (const float*)d_in[13];

    float* out = (float*)d_out;
    vf4* outq  = (vf4*)d_out;

    // workspace layout
    char* wp = (char*)d_ws;
    double* c1hm = (double*)wp;                 wp += (size_t)NBATCH * CHN * NPIX * 8;
    double* hm_z = (double*)wp;                 wp += (size_t)NBATCH * NCLS * NPIX * 8;
    float*  c1wr = (float*)wp;                  wp += (size_t)2 * NBATCH * CHN * NPIX * 4;
    float*  wh   = (float*)wp;                  wp += (size_t)NBATCH * 2 * NPIX * 4;
    float*  rg   = (float*)wp;                  wp += (size_t)NBATCH * 2 * NPIX * 4;
    unsigned long long* ballots = (unsigned long long*)wp; wp += (size_t)NBATCH * 8000 * 8;
    unsigned int* counts = (unsigned int*)wp;

    conv1_kernel<<<480, 320, 0, stream>>>(
        x, hm_w1, hm_b1, wh_w1, wh_b1, reg_w1, reg_b1, c1hm, c1wr, outq);

    conv2_kernel<<<400, 256, 0, stream>>>(
        c1hm, hm_w2, hm_b2, c1wr, wh_w2, wh_b2, reg_w2, reg_b2,
        hm_z, wh, rg, outq);

    flags_kernel<<<dim3(NBLK, 2), 1024, 0, stream>>>(hm_z, ballots, counts, outq);

    scatter_kernel<<<dim3(NBLK, 2), 1024, 0, stream>>>(
        ballots, counts, hm_z, wh, rg, offsets, out);
}